// Round 15
// baseline (249.411 us; speedup 1.0000x reference)
//
#include <hip/hip_runtime.h>
#include <math.h>

#define BATCH 32
#define NN 512
#define DD 256
#define NUMK 4

typedef __attribute__((ext_vector_type(8))) short bf16x8;
typedef __attribute__((ext_vector_type(4))) float f32x4;
typedef __attribute__((ext_vector_type(4))) unsigned short u16x4;

__device__ __forceinline__ float softplusf(float v) { return log1pf(expf(v)); }

__device__ __forceinline__ unsigned enc_key(float v) {
  unsigned u = __float_as_uint(v);
  return (u & 0x80000000u) ? ~u : (u | 0x80000000u);
}
__device__ __forceinline__ float dec_key(unsigned k) {
  return (k & 0x80000000u) ? __uint_as_float(k & 0x7fffffffu) : __uint_as_float(~k);
}
__device__ __forceinline__ unsigned short f2b(float f) {
  unsigned u = __float_as_uint(f);
  unsigned r = (u + 0x7fffu + ((u >> 16) & 1u)) >> 16;
  return (unsigned short)r;
}
__device__ __forceinline__ float b2f(unsigned short h) {
  return __uint_as_float(((unsigned)h) << 16);
}

#define GLDS(gp, lp)                                                   \
  __builtin_amdgcn_global_load_lds(                                    \
      (__attribute__((address_space(1))) void*)(void*)(gp),            \
      (__attribute__((address_space(3))) void*)(lp), 16, 0, 0)

// ---------- prep: xb=bf16(x)[n][d], xTb=bf16(x^T)[d][n]; zero keys ----------
__global__ __launch_bounds__(256) void k_prep(const float* __restrict__ x,
                                              short* __restrict__ xb,
                                              short* __restrict__ xTb,
                                              unsigned* keys) {
  __shared__ float t[64][65];
  int b = blockIdx.z, n0 = blockIdx.y * 64, d0 = blockIdx.x * 64;
  if (blockIdx.x == 0 && blockIdx.y == 0 && blockIdx.z == 0 && threadIdx.x == 0) {
    keys[0] = 0u; keys[1] = 0u;
  }
  const float* X = x + (size_t)b * NN * DD;
  int col = threadIdx.x & 63, rr = threadIdx.x >> 6;
#pragma unroll
  for (int s = 0; s < 16; ++s) {
    int row = s * 4 + rr;
    float v = X[(size_t)(n0 + row) * DD + d0 + col];
    t[row][col] = v;
    xb[(size_t)b * NN * DD + (size_t)(n0 + row) * DD + d0 + col] = (short)f2b(v);
  }
  __syncthreads();
#pragma unroll
  for (int s = 0; s < 16; ++s) {
    int row = s * 4 + rr;
    xTb[(size_t)b * DD * NN + (size_t)(d0 + row) * NN + n0 + col] = (short)f2b(t[col][row]);
  }
}

// ---------- c1 Gram (32x32 tiles, high occupancy) + fused rnmax job ----------
// grid (BATCH, 65): job<64 -> c1 tile; job==64 -> max(c2)=max_n ||x_n||^2/D from xTb.
__global__ __launch_bounds__(256) void k_c1(const short* __restrict__ xTb,
                                            short* __restrict__ c1b,
                                            unsigned* keys) {
  __shared__ short As[32 * 64];
  __shared__ short Bs[32 * 64];
  __shared__ float smf[4];
  const int b = blockIdx.x;
  const int job = blockIdx.y;
  const int tid = threadIdx.x, wave = tid >> 6, lane = tid & 63;

  if (job == 64) {
    // row-norm max via xTb columns (coalesced): thread t owns n = 2t, 2t+1
    const short* XT = xTb + (size_t)b * ((size_t)DD * NN);
    float s0 = 0.f, s1 = 0.f;
    for (int d = 0; d < DD; ++d) {
      unsigned vv = *(const unsigned*)(XT + (size_t)d * NN + tid * 2);
      float f0 = b2f((unsigned short)(vv & 0xffffu));
      float f1 = b2f((unsigned short)(vv >> 16));
      s0 += f0 * f0;
      s1 += f1 * f1;
    }
    float m = fmaxf(s0, s1);
#pragma unroll
    for (int o = 32; o > 0; o >>= 1) m = fmaxf(m, __shfl_xor(m, o));
    if (lane == 0) smf[wave] = m;
    __syncthreads();
    if (tid == 0) {
      float mm = fmaxf(fmaxf(smf[0], smf[1]), fmaxf(smf[2], smf[3])) * (1.0f / DD);
      atomicMax(keys + 1, enc_key(mm));
    }
    return;
  }

  const int m0 = (job >> 3) * 32, n0 = (job & 7) * 32;
  const int ln = lane & 15, kg = lane >> 4;
  const int wr = (wave >> 1) * 16, wc = (wave & 1) * 16;
  const short* Ab = xTb + (size_t)b * ((size_t)NN * DD);

  f32x4 acc = (f32x4){0.f, 0.f, 0.f, 0.f};
  for (int k0 = 0; k0 < NN; k0 += 64) {
    __syncthreads();
    {
      int row = wave * 8 + (lane >> 3);
      int sg = (lane & 7) ^ (row & 7);
      GLDS(Ab + (size_t)(m0 + row) * NN + k0 + sg * 8, &As[(wave * 8) * 64]);
      GLDS(Ab + (size_t)(n0 + row) * NN + k0 + sg * 8, &Bs[(wave * 8) * 64]);
    }
    __syncthreads();
    bf16x8 af[2], bfr[2];
#pragma unroll
    for (int kk = 0; kk < 2; ++kk) {
      int rowA = wr + ln;
      af[kk] = *(const bf16x8*)&As[rowA * 64 + (((kk * 4 + kg) ^ (rowA & 7)) * 8)];
      int rowB = wc + ln;
      bfr[kk] = *(const bf16x8*)&Bs[rowB * 64 + (((kk * 4 + kg) ^ (rowB & 7)) * 8)];
    }
#pragma unroll
    for (int kk = 0; kk < 2; ++kk)
      acc = __builtin_amdgcn_mfma_f32_16x16x32_bf16(af[kk], bfr[kk], acc, 0, 0, 0);
  }

  unsigned short* ot = (unsigned short*)c1b + (size_t)b * ((size_t)DD * DD);
  int r0 = m0 + wr + kg * 4;
  int c = n0 + wc + ln;
  float tmax = -1e30f;
  u16x4 pk;
#pragma unroll
  for (int q = 0; q < 4; ++q) {
    float v = acc[q] * (1.0f / NN);
    tmax = fmaxf(tmax, v);
    pk[q] = f2b(v);
  }
  *(u16x4*)&ot[(size_t)c * DD + r0] = pk;
#pragma unroll
  for (int o = 32; o > 0; o >>= 1) tmax = fmaxf(tmax, __shfl_xor(tmax, o));
  if (lane == 0) smf[wave] = tmax;
  __syncthreads();
  if (tid == 0)
    atomicMax(keys, enc_key(fmaxf(fmaxf(smf[0], smf[1]), fmaxf(smf[2], smf[3]))));
}

// ---------- misc: s1 = rowsum(c1b), S = colsum(xb), scalar params ----------
__global__ __launch_bounds__(256) void k_misc(const short* __restrict__ c1b,
                                              const short* __restrict__ xb,
                                              float* __restrict__ s1,
                                              float* __restrict__ S,
                                              const float* a0p, const float* a1p,
                                              const float* a2p, const float* a3p,
                                              const float* rhop, float* P,
                                              const unsigned* keys) {
  int bid = blockIdx.x;
  int lane = threadIdx.x & 63;
  if (bid < 2048) {
    int row = bid * 4 + (threadIdx.x >> 6);
    u16x4 v = *(const u16x4*)(c1b + (size_t)row * 256 + lane * 4);
    float s = 0.f;
#pragma unroll
    for (int q = 0; q < 4; ++q) s += b2f(v[q]);
#pragma unroll
    for (int o = 32; o > 0; o >>= 1) s += __shfl_xor(s, o);
    if (lane == 0) s1[row] = s;
  } else if (bid < 2080) {
    int b = bid - 2048;
    int d = threadIdx.x;
    const short* X = xb + (size_t)b * NN * DD;
    float s = 0.f;
    for (int n = 0; n < NN; ++n) s += b2f((unsigned short)X[(size_t)n * DD + d]);
    S[(size_t)b * DD + d] = s;
  } else if (threadIdx.x == 0) {
    float M1 = dec_key(keys[0]);
    float M2 = dec_key(keys[1]);
    float lq0 = logf(1.0f / NN + 1e-8f);
    float lp0 = logf(1.0f / DD + 1e-8f);
    float mu = lq0, eta = lp0, z1 = 0.f, z2 = 0.f;
    for (int k = 0; k < NUMK; ++k) {
      float a0 = softplusf(a0p[k]), a1 = softplusf(a1p[k]);
      float a2 = softplusf(a2p[k]), a3 = softplusf(a3p[k]);
      float rho = softplusf(rhop[k]);
      P[0 + k] = a0;
      P[4 + k] = a1 / (M1 * M2);
      P[8 + k] = rho;
      P[12 + k] = mu;
      P[16 + k] = eta;
      float t1 = mu;
      mu = (a2 * lq0 + rho * t1 - z1) / (a2 + rho);
      z1 += rho * (expf(mu) - expf(t1));
      float s1v = eta;
      eta = (a3 * lp0 + rho * s1v - z2) / (a3 + rho);
      z2 += rho * (expf(eta) - expf(s1v));
    }
  }
}

// ---------- GEMM for F / Mt: 32x32 tile, BK=64, high occupancy ----------
// OUTK 1: bf16 natural store                               (F = x^T @ E)
// OUTK 2: bf16 transposed store, scale P[4+k]/DD           (Mt_S)
// OUTK 3: same as 2 plus identity on diagonal              (Mt_T)
template <int K, int OUTK>
__global__ __launch_bounds__(256) void k_gemm(
    const short* __restrict__ A, size_t sA, int lda,
    const short* __restrict__ Bp, size_t sB, int ldb,
    void* __restrict__ outp, size_t sO, int ldo,
    const float* __restrict__ P, int kiter) {
  __shared__ short As[32 * 64];
  __shared__ short Bs[32 * 64];
  const int b = blockIdx.x;
  const int m0 = blockIdx.y * 32, n0 = blockIdx.z * 32;
  const int tid = threadIdx.x, wave = tid >> 6, lane = tid & 63;
  const int ln = lane & 15, kg = lane >> 4;
  const int wr = (wave >> 1) * 16, wc = (wave & 1) * 16;
  const short* Ab = A + (size_t)b * sA;
  const short* Bb = Bp + (size_t)b * sB;

  f32x4 acc = (f32x4){0.f, 0.f, 0.f, 0.f};
  for (int k0 = 0; k0 < K; k0 += 64) {
    __syncthreads();
    {
      int row = wave * 8 + (lane >> 3);
      int sg = (lane & 7) ^ (row & 7);
      GLDS(Ab + (size_t)(m0 + row) * lda + k0 + sg * 8, &As[(wave * 8) * 64]);
      GLDS(Bb + (size_t)(n0 + row) * ldb + k0 + sg * 8, &Bs[(wave * 8) * 64]);
    }
    __syncthreads();
    bf16x8 af[2], bfr[2];
#pragma unroll
    for (int kk = 0; kk < 2; ++kk) {
      int rowA = wr + ln;
      af[kk] = *(const bf16x8*)&As[rowA * 64 + (((kk * 4 + kg) ^ (rowA & 7)) * 8)];
      int rowB = wc + ln;
      bfr[kk] = *(const bf16x8*)&Bs[rowB * 64 + (((kk * 4 + kg) ^ (rowB & 7)) * 8)];
    }
#pragma unroll
    for (int kk = 0; kk < 2; ++kk)
      acc = __builtin_amdgcn_mfma_f32_16x16x32_bf16(af[kk], bfr[kk], acc, 0, 0, 0);
  }

  unsigned short* ot = (unsigned short*)outp + (size_t)b * sO;
  if (OUTK >= 2) {
    float sc = P[4 + kiter] * (1.0f / DD);
    int r0 = m0 + wr + kg * 4;
    int c = n0 + wc + ln;
    u16x4 pk;
#pragma unroll
    for (int q = 0; q < 4; ++q) {
      float v = acc[q] * sc;
      if (OUTK == 3 && c == r0 + q) v += 1.0f;
      pk[q] = f2b(v);
    }
    *(u16x4*)&ot[(size_t)c * ldo + r0] = pk;
  } else {
    int c = n0 + wc + ln;
#pragma unroll
    for (int q = 0; q < 4; ++q) {
      int r = m0 + wr + kg * 4 + q;
      ot[(size_t)r * ldo + c] = f2b(acc[q]);
    }
  }
}

// ---------- k=0 T-half: rank-1 shortcut (coalesced: lane = n) ----------
__global__ __launch_bounds__(512) void k_tsm0(
    const short* __restrict__ xTb, const float* __restrict__ S,
    const float* __restrict__ s1, short* __restrict__ eTT,
    const float* __restrict__ P) {
  const int b = blockIdx.x;
  const int n = blockIdx.y * 64 + (threadIdx.x & 63);
  const int wave = threadIdx.x >> 6, lane = threadIdx.x & 63;
  const size_t base = (size_t)b * ((size_t)NN * DD);
  __shared__ float red[8][64];
  float y[32];
  float dot = 0.f;
#pragma unroll
  for (int dk = 0; dk < 32; ++dk) {
    int d = wave * 32 + dk;
    float v = b2f((unsigned short)xTb[base + (size_t)d * NN + n]);
    y[dk] = v;
    dot += v * S[(size_t)b * DD + d];
  }
  red[wave][lane] = dot;
  __syncthreads();
  dot = 0.f;
#pragma unroll
  for (int w = 0; w < 8; ++w) dot += red[w][lane];
  const float c0 = logf(1.0f / NN + 1e-8f) + logf(1.0f / DD + 1e-8f);
  const float g = P[4] * expf(c0) * dot * (1.0f / DD);
  const float inv = 1.0f / (P[8] + P[0]);
  float m = -1e30f;
#pragma unroll
  for (int dk = 0; dk < 32; ++dk) {
    int d = wave * 32 + dk;
    y[dk] = (y[dk] + g * s1[(size_t)b * DD + d]) * inv;
    m = fmaxf(m, y[dk]);
  }
  __syncthreads();
  red[wave][lane] = m;
  __syncthreads();
#pragma unroll
  for (int w = 0; w < 8; ++w) m = fmaxf(m, red[w][lane]);
  float s = 0.f;
#pragma unroll
  for (int dk = 0; dk < 32; ++dk) s += expf(y[dk] - m);
  __syncthreads();
  red[wave][lane] = s;
  __syncthreads();
  s = 0.f;
#pragma unroll
  for (int w = 0; w < 8; ++w) s += red[w][lane];
  const float lse = m + logf(s);
  const float mu = P[12];
#pragma unroll
  for (int dk = 0; dk < 32; ++dk) {
    int d = wave * 32 + dk;
    eTT[base + (size_t)d * NN + n] = (short)f2b(expf(mu + y[dk] - lse));
  }
}

// ---------- fused T-half (k>=1): GEMM(x@Mt_T) + T-softmax(axis=d) [LDS-staged] ----------
template <int LAST>
__global__ __launch_bounds__(256) void k_ft(
    const short* __restrict__ xb, const short* __restrict__ Mtb,
    const short* __restrict__ eST, const short* __restrict__ zb,
    short* __restrict__ eTT, const short* __restrict__ xTb,
    float* __restrict__ part, const float* __restrict__ P, int kiter) {
  __shared__ short As[32 * 64];   // xb n-tile
  __shared__ short Bs[256 * 64];  // Mt d rows
  const int b = blockIdx.x, m0 = blockIdx.y * 32;
  const int tid = threadIdx.x, wave = tid >> 6, lane = tid & 63;
  const int ln = lane & 15, kg = lane >> 4;
  const short* Ab = xb + (size_t)b * ((size_t)NN * DD);
  const short* Bb = Mtb + (size_t)b * ((size_t)DD * DD);
  const size_t base = (size_t)b * ((size_t)NN * DD);

  f32x4 acc[2][4];
#pragma unroll
  for (int i = 0; i < 2; ++i)
#pragma unroll
    for (int j = 0; j < 4; ++j) acc[i][j] = (f32x4){0.f, 0.f, 0.f, 0.f};

  for (int k0 = 0; k0 < DD; k0 += 64) {
    __syncthreads();
    {
      int row = wave * 8 + (lane >> 3);
      int sg = (lane & 7) ^ (row & 7);
      GLDS(Ab + (size_t)(m0 + row) * DD + k0 + sg * 8, &As[(wave * 8) * 64]);
    }
#pragma unroll
    for (int c = 0; c < 8; ++c) {
      int row = wave * 64 + c * 8 + (lane >> 3);
      int sg = (lane & 7) ^ (row & 7);
      GLDS(Bb + (size_t)row * DD + k0 + sg * 8, &Bs[(wave * 64 + c * 8) * 64]);
    }
    __syncthreads();
    bf16x8 af[2][2], bfr[4][2];
#pragma unroll
    for (int i = 0; i < 2; ++i)
#pragma unroll
      for (int kk = 0; kk < 2; ++kk) {
        int rowA = i * 16 + ln;
        af[i][kk] = *(const bf16x8*)&As[rowA * 64 + (((kk * 4 + kg) ^ (rowA & 7)) * 8)];
      }
#pragma unroll
    for (int j = 0; j < 4; ++j)
#pragma unroll
      for (int kk = 0; kk < 2; ++kk) {
        int rowB = wave * 64 + j * 16 + ln;
        bfr[j][kk] = *(const bf16x8*)&Bs[rowB * 64 + (((kk * 4 + kg) ^ (rowB & 7)) * 8)];
      }
#pragma unroll
    for (int kk = 0; kk < 2; ++kk)
#pragma unroll
      for (int i = 0; i < 2; ++i)
#pragma unroll
        for (int j = 0; j < 4; ++j)
          acc[i][j] = __builtin_amdgcn_mfma_f32_16x16x32_bf16(af[i][kk], bfr[j][kk],
                                                              acc[i][j], 0, 0, 0);
  }
  __syncthreads();
  float* red = (float*)As;

  const float a0 = P[kiter], rho = P[8 + kiter], mu = P[12 + kiter];
  const float inv = 1.0f / (rho + a0);
  float y[2][4][4];
#pragma unroll
  for (int i = 0; i < 2; ++i)
#pragma unroll
    for (int j = 0; j < 4; ++j) {
      int d = wave * 64 + j * 16 + ln;
      int n4 = m0 + i * 16 + kg * 4;
      size_t idx = base + (size_t)d * NN + n4;
      u16x4 zv = *(const u16x4*)&zb[idx];
      u16x4 es = *(const u16x4*)&eST[idx];
#pragma unroll
      for (int q = 0; q < 4; ++q)
        y[i][j][q] = (acc[i][j][q] + b2f(zv[q]) + rho * logf(b2f(es[q]))) * inv;
    }
  float pm[2][4];
#pragma unroll
  for (int i = 0; i < 2; ++i)
#pragma unroll
    for (int q = 0; q < 4; ++q) {
      float m = fmaxf(fmaxf(y[i][0][q], y[i][1][q]), fmaxf(y[i][2][q], y[i][3][q]));
      m = fmaxf(m, __shfl_xor(m, 1));
      m = fmaxf(m, __shfl_xor(m, 2));
      m = fmaxf(m, __shfl_xor(m, 4));
      m = fmaxf(m, __shfl_xor(m, 8));
      pm[i][q] = m;
    }
  if (ln == 0) {
#pragma unroll
    for (int i = 0; i < 2; ++i)
#pragma unroll
      for (int q = 0; q < 4; ++q) red[wave * 32 + i * 16 + kg * 4 + q] = pm[i][q];
  }
  __syncthreads();
  if (tid < 32)
    red[128 + tid] = fmaxf(fmaxf(red[tid], red[32 + tid]),
                           fmaxf(red[64 + tid], red[96 + tid]));
  __syncthreads();
  float sm[2][4], mc[2][4];
#pragma unroll
  for (int i = 0; i < 2; ++i)
#pragma unroll
    for (int q = 0; q < 4; ++q) {
      mc[i][q] = red[128 + i * 16 + kg * 4 + q];
      float s = expf(y[i][0][q] - mc[i][q]) + expf(y[i][1][q] - mc[i][q]) +
                expf(y[i][2][q] - mc[i][q]) + expf(y[i][3][q] - mc[i][q]);
      s += __shfl_xor(s, 1);
      s += __shfl_xor(s, 2);
      s += __shfl_xor(s, 4);
      s += __shfl_xor(s, 8);
      sm[i][q] = s;
    }
  __syncthreads();
  if (ln == 0) {
#pragma unroll
    for (int i = 0; i < 2; ++i)
#pragma unroll
      for (int q = 0; q < 4; ++q) red[wave * 32 + i * 16 + kg * 4 + q] = sm[i][q];
  }
  __syncthreads();
  if (tid < 32)
    red[160 + tid] = red[128 + tid] +
                     logf(red[tid] + red[32 + tid] + red[64 + tid] + red[96 + tid]);
  __syncthreads();
  float lse[2][4];
#pragma unroll
  for (int i = 0; i < 2; ++i)
#pragma unroll
    for (int q = 0; q < 4; ++q) lse[i][q] = red[160 + i * 16 + kg * 4 + q];

  if (LAST == 0) {
#pragma unroll
    for (int i = 0; i < 2; ++i)
#pragma unroll
      for (int j = 0; j < 4; ++j) {
        int d = wave * 64 + j * 16 + ln;
        int n4 = m0 + i * 16 + kg * 4;
        size_t idx = base + (size_t)d * NN + n4;
        u16x4 et;
#pragma unroll
        for (int q = 0; q < 4; ++q) et[q] = f2b(expf(mu + y[i][j][q] - lse[i][q]));
        *(u16x4*)&eTT[idx] = et;
      }
  } else {
    float p[4] = {0.f, 0.f, 0.f, 0.f};
#pragma unroll
    for (int j = 0; j < 4; ++j)
#pragma unroll
      for (int i = 0; i < 2; ++i) {
        int d = wave * 64 + j * 16 + ln;
        int n4 = m0 + i * 16 + kg * 4;
        size_t idx = base + (size_t)d * NN + n4;
        u16x4 xv = *(const u16x4*)&xTb[idx];
#pragma unroll
        for (int q = 0; q < 4; ++q)
          p[j] += b2f(xv[q]) * expf(mu + y[i][j][q] - lse[i][q]);
      }
#pragma unroll
    for (int j = 0; j < 4; ++j) {
      p[j] += __shfl_xor(p[j], 16);
      p[j] += __shfl_xor(p[j], 32);
    }
    if (kg == 0) {
      size_t pb = ((size_t)b * 16 + blockIdx.y) * DD;
#pragma unroll
      for (int j = 0; j < 4; ++j) part[pb + wave * 64 + j * 16 + ln] = p[j];
    }
  }
}

// ---------- fused S-half: GEMM(x@Mt_S) + S-softmax(axis=n) + z-update [LDS-staged] ----------
template <int ZFIRST>
__global__ __launch_bounds__(512) void k_fs(
    const short* __restrict__ xb, const short* __restrict__ Mtb,
    const short* __restrict__ eTT, short* __restrict__ eST,
    short* __restrict__ zb, const float* __restrict__ P, int kiter) {
  __shared__ short As[512 * 32];
  __shared__ short Bs[32 * 32];
  const int b = blockIdx.x, m0 = blockIdx.y * 32;
  const int tid = threadIdx.x, wave = tid >> 6, lane = tid & 63;
  const int ln = lane & 15, kg = lane >> 4;
  const short* Ab = xb + (size_t)b * ((size_t)NN * DD);
  const short* Bb = Mtb + (size_t)b * ((size_t)DD * DD);
  const size_t base = (size_t)b * ((size_t)NN * DD);

  f32x4 acc[4][2];
#pragma unroll
  for (int i = 0; i < 4; ++i)
#pragma unroll
    for (int j = 0; j < 2; ++j) acc[i][j] = (f32x4){0.f, 0.f, 0.f, 0.f};

  for (int k0 = 0; k0 < DD; k0 += 32) {
    __syncthreads();
#pragma unroll
    for (int c = 0; c < 4; ++c) {
      int row = wave * 64 + c * 16 + (lane >> 2);
      int sg = (lane & 3) ^ (row & 3);
      GLDS(Ab + (size_t)row * DD + k0 + sg * 8, &As[(wave * 64 + c * 16) * 32]);
    }
    if (wave < 2) {
      int row = wave * 16 + (lane >> 2);
      int sg = (lane & 3) ^ (row & 3);
      GLDS(Bb + (size_t)(m0 + row) * DD + k0 + sg * 8, &Bs[(wave * 16) * 32]);
    }
    __syncthreads();
    bf16x8 af[4], bfr[2];
#pragma unroll
    for (int i = 0; i < 4; ++i) {
      int rowA = wave * 64 + i * 16 + ln;
      af[i] = *(const bf16x8*)&As[rowA * 32 + ((kg ^ (rowA & 3)) * 8)];
    }
#pragma unroll
    for (int j = 0; j < 2; ++j) {
      int rowB = j * 16 + ln;
      bfr[j] = *(const bf16x8*)&Bs[rowB * 32 + ((kg ^ (rowB & 3)) * 8)];
    }
#pragma unroll
    for (int i = 0; i < 4; ++i)
#pragma unroll
      for (int j = 0; j < 2; ++j)
        acc[i][j] = __builtin_amdgcn_mfma_f32_16x16x32_bf16(af[i], bfr[j], acc[i][j], 0, 0, 0);
  }
  __syncthreads();
  float* red = (float*)Bs;

  const float rho = P[8 + kiter], eta = P[16 + kiter];
  const float invr = 1.0f / rho;
  float y[4][2][4];
  u16x4 etr[4][2], zr[4][2];
#pragma unroll
  for (int i = 0; i < 4; ++i)
#pragma unroll
    for (int j = 0; j < 2; ++j) {
      int d = m0 + j * 16 + ln;
      int n4 = wave * 64 + i * 16 + kg * 4;
      size_t idx = base + (size_t)d * NN + n4;
      etr[i][j] = *(const u16x4*)&eTT[idx];
      if (!ZFIRST) zr[i][j] = *(const u16x4*)&zb[idx];
#pragma unroll
      for (int q = 0; q < 4; ++q) {
        float zf = ZFIRST ? 0.0f : b2f(zr[i][j][q]);
        y[i][j][q] = (acc[i][j][q] - zf + rho * logf(b2f(etr[i][j][q]))) * invr;
      }
    }
  float pm[2];
#pragma unroll
  for (int j = 0; j < 2; ++j) {
    float m = -1e30f;
#pragma unroll
    for (int i = 0; i < 4; ++i)
#pragma unroll
      for (int q = 0; q < 4; ++q) m = fmaxf(m, y[i][j][q]);
    m = fmaxf(m, __shfl_xor(m, 16));
    m = fmaxf(m, __shfl_xor(m, 32));
    pm[j] = m;
  }
  if (kg == 0) {
#pragma unroll
    for (int j = 0; j < 2; ++j) red[wave * 32 + j * 16 + ln] = pm[j];
  }
  __syncthreads();
  if (tid < 32) {
    float M = red[tid];
#pragma unroll
    for (int w = 1; w < 8; ++w) M = fmaxf(M, red[w * 32 + tid]);
    red[256 + tid] = M;
  }
  __syncthreads();
  float mc[2], ps[2];
#pragma unroll
  for (int j = 0; j < 2; ++j) {
    mc[j] = red[256 + j * 16 + ln];
    float s = 0.f;
#pragma unroll
    for (int i = 0; i < 4; ++i)
#pragma unroll
      for (int q = 0; q < 4; ++q) s += expf(y[i][j][q] - mc[j]);
    s += __shfl_xor(s, 16);
    s += __shfl_xor(s, 32);
    ps[j] = s;
  }
  __syncthreads();
  if (kg == 0) {
#pragma unroll
    for (int j = 0; j < 2; ++j) red[wave * 32 + j * 16 + ln] = ps[j];
  }
  __syncthreads();
  if (tid < 32) {
    float S = 0.f;
#pragma unroll
    for (int w = 0; w < 8; ++w) S += red[w * 32 + tid];
    red[288 + tid] = red[256 + tid] + logf(S);
  }
  __syncthreads();
  float lse[2];
#pragma unroll
  for (int j = 0; j < 2; ++j) lse[j] = red[288 + j * 16 + ln];

#pragma unroll
  for (int i = 0; i < 4; ++i)
#pragma unroll
    for (int j = 0; j < 2; ++j) {
      int d = m0 + j * 16 + ln;
      int n4 = wave * 64 + i * 16 + kg * 4;
      size_t idx = base + (size_t)d * NN + n4;
      u16x4 ev, zo;
#pragma unroll
      for (int q = 0; q < 4; ++q) {
        float es = expf(eta + y[i][j][q] - lse[j]);
        ev[q] = f2b(es);
        float zf = ZFIRST ? 0.0f : b2f(zr[i][j][q]);
        zo[q] = f2b(zf + rho * (b2f(etr[i][j][q]) - es));
      }
      *(u16x4*)&eST[idx] = ev;
      *(u16x4*)&zb[idx] = zo;
    }
}

// ---------- final reduce: out[b][d] = D * sum over 16 partial chunks ----------
__global__ __launch_bounds__(256) void k_out2(const float* __restrict__ part,
                                              float* __restrict__ out) {
  int b = blockIdx.x, d = threadIdx.x;
  float acc = 0.0f;
#pragma unroll
  for (int c = 0; c < 16; ++c) acc += part[((size_t)b * 16 + c) * DD + d];
  out[(size_t)b * DD + d] = (float)DD * acc;
}

// ---------- launch ----------
extern "C" void kernel_launch(void* const* d_in, const int* in_sizes, int n_in,
                              void* d_out, int out_size, void* d_ws, size_t ws_size,
                              hipStream_t stream) {
  const float* x = (const float*)d_in[0];
  const float* a0p = (const float*)d_in[1];
  const float* a1p = (const float*)d_in[2];
  const float* a2p = (const float*)d_in[3];
  const float* a3p = (const float*)d_in[4];
  const float* rhop = (const float*)d_in[5];
  float* out = (float*)d_out;

  const size_t NE = (size_t)BATCH * NN * DD;
  const size_t NE_b = (size_t)NN * DD;
  const size_t C1_b = (size_t)DD * DD;

  float* fws = (float*)d_ws;
  float* S = fws;                   // B*D colsum(x)
  float* s1 = S + BATCH * DD;       // B*D rowsum(c1)
  float* part = s1 + BATCH * DD;    // B*16*DD
  float* P = part + BATCH * 16 * DD;  // 24
  unsigned* keys = (unsigned*)(P + 24);
  short* sws = (short*)(keys + 8);
  short* xb = sws;                  // NE (n-major bf16)
  short* xTb = sws + NE;            // NE (d-major bf16)
  short* eTT = sws + 2 * NE;        // NE (d-major)
  short* eST = sws + 3 * NE;        // NE (d-major)
  short* zb = sws + 4 * NE;         // NE (d-major bf16 dual)
  short* Fb = sws + 5 * NE;         // B*D*D
  short* Mtb = Fb + (size_t)BATCH * C1_b;   // B*D*D
  short* c1b = Mtb + (size_t)BATCH * C1_b;  // B*D*D

  k_prep<<<dim3(4, 8, BATCH), 256, 0, stream>>>(x, xb, xTb, keys);
  k_c1<<<dim3(BATCH, 65), 256, 0, stream>>>(xTb, c1b, keys);
  k_misc<<<2081, 256, 0, stream>>>(c1b, xb, s1, S, a0p, a1p, a2p, a3p, rhop, P, keys);

  // k = 0 T-half: rank-1 shortcut -> eTT
  k_tsm0<<<dim3(BATCH, 8), 512, 0, stream>>>(xTb, S, s1, eTT, P);
  // k = 0 S-half
  k_gemm<512, 1><<<dim3(BATCH, 8, 8), 256, 0, stream>>>(
      xTb, NE_b, NN, eTT, NE_b, NN, (void*)Fb, C1_b, DD, nullptr, 0);
  k_gemm<256, 2><<<dim3(BATCH, 8, 8), 256, 0, stream>>>(
      Fb, C1_b, DD, c1b, C1_b, DD, (void*)Mtb, C1_b, DD, P, 0);
  k_fs<1><<<dim3(BATCH, 8), 512, 0, stream>>>(xb, Mtb, eTT, eST, zb, P, 0);

  for (int k = 1; k <= 2; ++k) {
    // T-half: Mt_T = (a1e/D)(F(eS)@c1)^T + I; fused GEMM+softmax -> eTT
    k_gemm<512, 1><<<dim3(BATCH, 8, 8), 256, 0, stream>>>(
        xTb, NE_b, NN, eST, NE_b, NN, (void*)Fb, C1_b, DD, nullptr, 0);
    k_gemm<256, 3><<<dim3(BATCH, 8, 8), 256, 0, stream>>>(
        Fb, C1_b, DD, c1b, C1_b, DD, (void*)Mtb, C1_b, DD, P, k);
    k_ft<0><<<dim3(BATCH, 16), 256, 0, stream>>>(xb, Mtb, eST, zb, eTT, xTb,
                                                 part, P, k);
    // S-half
    k_gemm<512, 1><<<dim3(BATCH, 8, 8), 256, 0, stream>>>(
        xTb, NE_b, NN, eTT, NE_b, NN, (void*)Fb, C1_b, DD, nullptr, 0);
    k_gemm<256, 2><<<dim3(BATCH, 8, 8), 256, 0, stream>>>(
        Fb, C1_b, DD, c1b, C1_b, DD, (void*)Mtb, C1_b, DD, P, k);
    k_fs<0><<<dim3(BATCH, 8), 512, 0, stream>>>(xb, Mtb, eTT, eST, zb, P, k);
  }

  // k = 3: final T-half -> output partials (tail-trim: S-half dead)
  k_gemm<512, 1><<<dim3(BATCH, 8, 8), 256, 0, stream>>>(
      xTb, NE_b, NN, eST, NE_b, NN, (void*)Fb, C1_b, DD, nullptr, 0);
  k_gemm<256, 3><<<dim3(BATCH, 8, 8), 256, 0, stream>>>(
      Fb, C1_b, DD, c1b, C1_b, DD, (void*)Mtb, C1_b, DD, P, 3);
  k_ft<1><<<dim3(BATCH, 16), 256, 0, stream>>>(xb, Mtb, eST, zb, eTT, xTb,
                                               part, P, 3);
  k_out2<<<BATCH, 256, 0, stream>>>(part, out);
}

// Round 16
// 232.639 us; speedup vs baseline: 1.0721x; 1.0721x over previous
//
#include <hip/hip_runtime.h>
#include <math.h>

#define BATCH 32
#define NN 512
#define DD 256
#define NUMK 4

typedef __attribute__((ext_vector_type(8))) short bf16x8;
typedef __attribute__((ext_vector_type(4))) float f32x4;
typedef __attribute__((ext_vector_type(4))) unsigned short u16x4;

__device__ __forceinline__ float softplusf(float v) { return log1pf(expf(v)); }

__device__ __forceinline__ unsigned enc_key(float v) {
  unsigned u = __float_as_uint(v);
  return (u & 0x80000000u) ? ~u : (u | 0x80000000u);
}
__device__ __forceinline__ float dec_key(unsigned k) {
  return (k & 0x80000000u) ? __uint_as_float(k & 0x7fffffffu) : __uint_as_float(~k);
}
__device__ __forceinline__ unsigned short f2b(float f) {
  unsigned u = __float_as_uint(f);
  unsigned r = (u + 0x7fffu + ((u >> 16) & 1u)) >> 16;
  return (unsigned short)r;
}
__device__ __forceinline__ float b2f(unsigned short h) {
  return __uint_as_float(((unsigned)h) << 16);
}

#define GLDS(gp, lp)                                                   \
  __builtin_amdgcn_global_load_lds(                                    \
      (__attribute__((address_space(1))) void*)(void*)(gp),            \
      (__attribute__((address_space(3))) void*)(lp), 16, 0, 0)

// ---------- prep: xb=bf16(x)[n][d], xTb=bf16(x^T)[d][n]; zero keys ----------
__global__ __launch_bounds__(256) void k_prep(const float* __restrict__ x,
                                              short* __restrict__ xb,
                                              short* __restrict__ xTb,
                                              unsigned* keys) {
  __shared__ float t[64][65];
  int b = blockIdx.z, n0 = blockIdx.y * 64, d0 = blockIdx.x * 64;
  if (blockIdx.x == 0 && blockIdx.y == 0 && blockIdx.z == 0 && threadIdx.x == 0) {
    keys[0] = 0u; keys[1] = 0u;
  }
  const float* X = x + (size_t)b * NN * DD;
  int col = threadIdx.x & 63, rr = threadIdx.x >> 6;
#pragma unroll
  for (int s = 0; s < 16; ++s) {
    int row = s * 4 + rr;
    float v = X[(size_t)(n0 + row) * DD + d0 + col];
    t[row][col] = v;
    xb[(size_t)b * NN * DD + (size_t)(n0 + row) * DD + d0 + col] = (short)f2b(v);
  }
  __syncthreads();
#pragma unroll
  for (int s = 0; s < 16; ++s) {
    int row = s * 4 + rr;
    xTb[(size_t)b * DD * NN + (size_t)(d0 + row) * NN + n0 + col] = (short)f2b(t[col][row]);
  }
}

// ---------- c1 Gram (64x64 tiles) + fused rnmax job ----------
// grid (BATCH, 17): job<16 -> c1 tile (4x4); job==16 -> max(c2)=max_n ||x_n||^2/D.
__global__ __launch_bounds__(256) void k_c1(const short* __restrict__ xTb,
                                            short* __restrict__ c1b,
                                            unsigned* keys) {
  __shared__ short As[64 * 64];
  __shared__ short Bs[64 * 64];
  const int b = blockIdx.x;
  const int job = blockIdx.y;
  const int tid = threadIdx.x, wave = tid >> 6, lane = tid & 63;

  if (job == 16) {
    // row-norm max via xTb columns (coalesced): thread t owns n = 2t, 2t+1
    __shared__ float smf2[4];
    const short* XT = xTb + (size_t)b * ((size_t)DD * NN);
    float s0 = 0.f, s1 = 0.f;
    for (int d = 0; d < DD; ++d) {
      unsigned vv = *(const unsigned*)(XT + (size_t)d * NN + tid * 2);
      float f0 = b2f((unsigned short)(vv & 0xffffu));
      float f1 = b2f((unsigned short)(vv >> 16));
      s0 += f0 * f0;
      s1 += f1 * f1;
    }
    float m = fmaxf(s0, s1);
#pragma unroll
    for (int o = 32; o > 0; o >>= 1) m = fmaxf(m, __shfl_xor(m, o));
    if (lane == 0) smf2[wave] = m;
    __syncthreads();
    if (tid == 0) {
      float mm = fmaxf(fmaxf(smf2[0], smf2[1]), fmaxf(smf2[2], smf2[3])) * (1.0f / DD);
      atomicMax(keys + 1, enc_key(mm));
    }
    return;
  }

  const int m0 = (job >> 2) * 64, n0 = (job & 3) * 64;
  const int ln = lane & 15, kg = lane >> 4;
  const int wr = (wave >> 1) * 32, wc = (wave & 1) * 32;
  const short* Ab = xTb + (size_t)b * ((size_t)NN * DD);

  f32x4 acc[2][2];
#pragma unroll
  for (int i = 0; i < 2; ++i)
#pragma unroll
    for (int j = 0; j < 2; ++j) acc[i][j] = (f32x4){0.f, 0.f, 0.f, 0.f};

  for (int k0 = 0; k0 < NN; k0 += 64) {
    __syncthreads();
#pragma unroll
    for (int p = 0; p < 2; ++p) {
      int row = p * 32 + wave * 8 + (lane >> 3);
      int sg = (lane & 7) ^ (row & 7);
      GLDS(Ab + (size_t)(m0 + row) * NN + k0 + sg * 8, &As[(p * 32 + wave * 8) * 64]);
      GLDS(Ab + (size_t)(n0 + row) * NN + k0 + sg * 8, &Bs[(p * 32 + wave * 8) * 64]);
    }
    __syncthreads();
    bf16x8 af[2][2], bfr[2][2];
#pragma unroll
    for (int i = 0; i < 2; ++i)
#pragma unroll
      for (int kk = 0; kk < 2; ++kk) {
        int rowA = wr + i * 16 + ln;
        af[i][kk] = *(const bf16x8*)&As[rowA * 64 + (((kk * 4 + kg) ^ (rowA & 7)) * 8)];
        int rowB = wc + i * 16 + ln;
        bfr[i][kk] = *(const bf16x8*)&Bs[rowB * 64 + (((kk * 4 + kg) ^ (rowB & 7)) * 8)];
      }
#pragma unroll
    for (int kk = 0; kk < 2; ++kk)
#pragma unroll
      for (int i = 0; i < 2; ++i)
#pragma unroll
        for (int j = 0; j < 2; ++j)
          acc[i][j] = __builtin_amdgcn_mfma_f32_16x16x32_bf16(af[i][kk], bfr[j][kk],
                                                              acc[i][j], 0, 0, 0);
  }

  unsigned short* ot = (unsigned short*)c1b + (size_t)b * ((size_t)DD * DD);
  float tmax = -1e30f;
#pragma unroll
  for (int i = 0; i < 2; ++i) {
    int r0 = m0 + wr + i * 16 + kg * 4;
#pragma unroll
    for (int j = 0; j < 2; ++j) {
      int c = n0 + wc + j * 16 + ln;
      u16x4 pk;
#pragma unroll
      for (int q = 0; q < 4; ++q) {
        float v = acc[i][j][q] * (1.0f / NN);
        tmax = fmaxf(tmax, v);
        pk[q] = f2b(v);
      }
      *(u16x4*)&ot[(size_t)c * DD + r0] = pk;
    }
  }
#pragma unroll
  for (int o = 32; o > 0; o >>= 1) tmax = fmaxf(tmax, __shfl_xor(tmax, o));
  __syncthreads();
  float* smf = (float*)As;
  if (lane == 0) smf[wave] = tmax;
  __syncthreads();
  if (tid == 0)
    atomicMax(keys, enc_key(fmaxf(fmaxf(smf[0], smf[1]), fmaxf(smf[2], smf[3]))));
}

// ---------- misc: s1 = rowsum(c1b), S = colsum(xb), scalar params ----------
__global__ __launch_bounds__(256) void k_misc(const short* __restrict__ c1b,
                                              const short* __restrict__ xb,
                                              float* __restrict__ s1,
                                              float* __restrict__ S,
                                              const float* a0p, const float* a1p,
                                              const float* a2p, const float* a3p,
                                              const float* rhop, float* P,
                                              const unsigned* keys) {
  int bid = blockIdx.x;
  int lane = threadIdx.x & 63;
  if (bid < 2048) {
    int row = bid * 4 + (threadIdx.x >> 6);
    u16x4 v = *(const u16x4*)(c1b + (size_t)row * 256 + lane * 4);
    float s = 0.f;
#pragma unroll
    for (int q = 0; q < 4; ++q) s += b2f(v[q]);
#pragma unroll
    for (int o = 32; o > 0; o >>= 1) s += __shfl_xor(s, o);
    if (lane == 0) s1[row] = s;
  } else if (bid < 2080) {
    int b = bid - 2048;
    int d = threadIdx.x;
    const short* X = xb + (size_t)b * NN * DD;
    float s = 0.f;
    for (int n = 0; n < NN; ++n) s += b2f((unsigned short)X[(size_t)n * DD + d]);
    S[(size_t)b * DD + d] = s;
  } else if (threadIdx.x == 0) {
    float M1 = dec_key(keys[0]);
    float M2 = dec_key(keys[1]);
    float lq0 = logf(1.0f / NN + 1e-8f);
    float lp0 = logf(1.0f / DD + 1e-8f);
    float mu = lq0, eta = lp0, z1 = 0.f, z2 = 0.f;
    for (int k = 0; k < NUMK; ++k) {
      float a0 = softplusf(a0p[k]), a1 = softplusf(a1p[k]);
      float a2 = softplusf(a2p[k]), a3 = softplusf(a3p[k]);
      float rho = softplusf(rhop[k]);
      P[0 + k] = a0;
      P[4 + k] = a1 / (M1 * M2);
      P[8 + k] = rho;
      P[12 + k] = mu;
      P[16 + k] = eta;
      float t1 = mu;
      mu = (a2 * lq0 + rho * t1 - z1) / (a2 + rho);
      z1 += rho * (expf(mu) - expf(t1));
      float s1v = eta;
      eta = (a3 * lp0 + rho * s1v - z2) / (a3 + rho);
      z2 += rho * (expf(eta) - expf(s1v));
    }
  }
}

// ---------- GEMM for F / Mt: 64x64 tile, BK=64 ----------
// OUTK 1: bf16 natural store                               (F = x^T @ E)
// OUTK 2: bf16 transposed store, scale P[4+k]/DD           (Mt_S)
// OUTK 3: same as 2 plus identity on diagonal              (Mt_T)
template <int K, int OUTK>
__global__ __launch_bounds__(256) void k_gemm(
    const short* __restrict__ A, size_t sA, int lda,
    const short* __restrict__ Bp, size_t sB, int ldb,
    void* __restrict__ outp, size_t sO, int ldo,
    const float* __restrict__ P, int kiter) {
  __shared__ short As[64 * 64];
  __shared__ short Bs[64 * 64];
  const int b = blockIdx.x;
  const int m0 = blockIdx.y * 64, n0 = blockIdx.z * 64;
  const int tid = threadIdx.x, wave = tid >> 6, lane = tid & 63;
  const int ln = lane & 15, kg = lane >> 4;
  const int wr = (wave >> 1) * 32, wc = (wave & 1) * 32;
  const short* Ab = A + (size_t)b * sA;
  const short* Bb = Bp + (size_t)b * sB;

  f32x4 acc[2][2];
#pragma unroll
  for (int i = 0; i < 2; ++i)
#pragma unroll
    for (int j = 0; j < 2; ++j) acc[i][j] = (f32x4){0.f, 0.f, 0.f, 0.f};

  for (int k0 = 0; k0 < K; k0 += 64) {
    __syncthreads();
#pragma unroll
    for (int p = 0; p < 2; ++p) {
      int row = p * 32 + wave * 8 + (lane >> 3);
      int sg = (lane & 7) ^ (row & 7);
      GLDS(Ab + (size_t)(m0 + row) * lda + k0 + sg * 8, &As[(p * 32 + wave * 8) * 64]);
      GLDS(Bb + (size_t)(n0 + row) * ldb + k0 + sg * 8, &Bs[(p * 32 + wave * 8) * 64]);
    }
    __syncthreads();
    bf16x8 af[2][2], bfr[2][2];
#pragma unroll
    for (int i = 0; i < 2; ++i)
#pragma unroll
      for (int kk = 0; kk < 2; ++kk) {
        int rowA = wr + i * 16 + ln;
        af[i][kk] = *(const bf16x8*)&As[rowA * 64 + (((kk * 4 + kg) ^ (rowA & 7)) * 8)];
        int rowB = wc + i * 16 + ln;
        bfr[i][kk] = *(const bf16x8*)&Bs[rowB * 64 + (((kk * 4 + kg) ^ (rowB & 7)) * 8)];
      }
#pragma unroll
    for (int kk = 0; kk < 2; ++kk)
#pragma unroll
      for (int i = 0; i < 2; ++i)
#pragma unroll
        for (int j = 0; j < 2; ++j)
          acc[i][j] = __builtin_amdgcn_mfma_f32_16x16x32_bf16(af[i][kk], bfr[j][kk],
                                                              acc[i][j], 0, 0, 0);
  }

  unsigned short* ot = (unsigned short*)outp + (size_t)b * sO;
  if (OUTK >= 2) {
    float sc = P[4 + kiter] * (1.0f / DD);
#pragma unroll
    for (int i = 0; i < 2; ++i) {
      int r0 = m0 + wr + i * 16 + kg * 4;
#pragma unroll
      for (int j = 0; j < 2; ++j) {
        int c = n0 + wc + j * 16 + ln;
        u16x4 pk;
#pragma unroll
        for (int q = 0; q < 4; ++q) {
          float v = acc[i][j][q] * sc;
          if (OUTK == 3 && c == r0 + q) v += 1.0f;
          pk[q] = f2b(v);
        }
        *(u16x4*)&ot[(size_t)c * ldo + r0] = pk;
      }
    }
  } else {
#pragma unroll
    for (int i = 0; i < 2; ++i)
#pragma unroll
      for (int j = 0; j < 2; ++j) {
        int c = n0 + wc + j * 16 + ln;
#pragma unroll
        for (int q = 0; q < 4; ++q) {
          int r = m0 + wr + i * 16 + kg * 4 + q;
          ot[(size_t)r * ldo + c] = f2b(acc[i][j][q]);
        }
      }
  }
}

// ---------- k=0 T-half: rank-1 shortcut (coalesced: lane = n) ----------
__global__ __launch_bounds__(512) void k_tsm0(
    const short* __restrict__ xTb, const float* __restrict__ S,
    const float* __restrict__ s1, short* __restrict__ eTT,
    const float* __restrict__ P) {
  const int b = blockIdx.x;
  const int n = blockIdx.y * 64 + (threadIdx.x & 63);
  const int wave = threadIdx.x >> 6, lane = threadIdx.x & 63;
  const size_t base = (size_t)b * ((size_t)NN * DD);
  __shared__ float red[8][64];
  float y[32];
  float dot = 0.f;
#pragma unroll
  for (int dk = 0; dk < 32; ++dk) {
    int d = wave * 32 + dk;
    float v = b2f((unsigned short)xTb[base + (size_t)d * NN + n]);
    y[dk] = v;
    dot += v * S[(size_t)b * DD + d];
  }
  red[wave][lane] = dot;
  __syncthreads();
  dot = 0.f;
#pragma unroll
  for (int w = 0; w < 8; ++w) dot += red[w][lane];
  const float c0 = logf(1.0f / NN + 1e-8f) + logf(1.0f / DD + 1e-8f);
  const float g = P[4] * expf(c0) * dot * (1.0f / DD);
  const float inv = 1.0f / (P[8] + P[0]);
  float m = -1e30f;
#pragma unroll
  for (int dk = 0; dk < 32; ++dk) {
    int d = wave * 32 + dk;
    y[dk] = (y[dk] + g * s1[(size_t)b * DD + d]) * inv;
    m = fmaxf(m, y[dk]);
  }
  __syncthreads();
  red[wave][lane] = m;
  __syncthreads();
#pragma unroll
  for (int w = 0; w < 8; ++w) m = fmaxf(m, red[w][lane]);
  float s = 0.f;
#pragma unroll
  for (int dk = 0; dk < 32; ++dk) s += expf(y[dk] - m);
  __syncthreads();
  red[wave][lane] = s;
  __syncthreads();
  s = 0.f;
#pragma unroll
  for (int w = 0; w < 8; ++w) s += red[w][lane];
  const float lse = m + logf(s);
  const float mu = P[12];
#pragma unroll
  for (int dk = 0; dk < 32; ++dk) {
    int d = wave * 32 + dk;
    eTT[base + (size_t)d * NN + n] = (short)f2b(expf(mu + y[dk] - lse));
  }
}

// ---------- fused T-half (k>=1): GEMM(x@Mt_T) + T-softmax(axis=d) [LDS-staged] ----------
template <int LAST>
__global__ __launch_bounds__(256) void k_ft(
    const short* __restrict__ xb, const short* __restrict__ Mtb,
    const short* __restrict__ eST, const short* __restrict__ zb,
    short* __restrict__ eTT, const short* __restrict__ xTb,
    float* __restrict__ part, const float* __restrict__ P, int kiter) {
  __shared__ short As[32 * 64];   // xb n-tile
  __shared__ short Bs[256 * 64];  // Mt d rows
  const int b = blockIdx.x, m0 = blockIdx.y * 32;
  const int tid = threadIdx.x, wave = tid >> 6, lane = tid & 63;
  const int ln = lane & 15, kg = lane >> 4;
  const short* Ab = xb + (size_t)b * ((size_t)NN * DD);
  const short* Bb = Mtb + (size_t)b * ((size_t)DD * DD);
  const size_t base = (size_t)b * ((size_t)NN * DD);

  f32x4 acc[2][4];
#pragma unroll
  for (int i = 0; i < 2; ++i)
#pragma unroll
    for (int j = 0; j < 4; ++j) acc[i][j] = (f32x4){0.f, 0.f, 0.f, 0.f};

  for (int k0 = 0; k0 < DD; k0 += 64) {
    __syncthreads();
    {
      int row = wave * 8 + (lane >> 3);
      int sg = (lane & 7) ^ (row & 7);
      GLDS(Ab + (size_t)(m0 + row) * DD + k0 + sg * 8, &As[(wave * 8) * 64]);
    }
#pragma unroll
    for (int c = 0; c < 8; ++c) {
      int row = wave * 64 + c * 8 + (lane >> 3);
      int sg = (lane & 7) ^ (row & 7);
      GLDS(Bb + (size_t)row * DD + k0 + sg * 8, &Bs[(wave * 64 + c * 8) * 64]);
    }
    __syncthreads();
    bf16x8 af[2][2], bfr[4][2];
#pragma unroll
    for (int i = 0; i < 2; ++i)
#pragma unroll
      for (int kk = 0; kk < 2; ++kk) {
        int rowA = i * 16 + ln;
        af[i][kk] = *(const bf16x8*)&As[rowA * 64 + (((kk * 4 + kg) ^ (rowA & 7)) * 8)];
      }
#pragma unroll
    for (int j = 0; j < 4; ++j)
#pragma unroll
      for (int kk = 0; kk < 2; ++kk) {
        int rowB = wave * 64 + j * 16 + ln;
        bfr[j][kk] = *(const bf16x8*)&Bs[rowB * 64 + (((kk * 4 + kg) ^ (rowB & 7)) * 8)];
      }
#pragma unroll
    for (int kk = 0; kk < 2; ++kk)
#pragma unroll
      for (int i = 0; i < 2; ++i)
#pragma unroll
        for (int j = 0; j < 4; ++j)
          acc[i][j] = __builtin_amdgcn_mfma_f32_16x16x32_bf16(af[i][kk], bfr[j][kk],
                                                              acc[i][j], 0, 0, 0);
  }
  __syncthreads();
  float* red = (float*)As;

  const float a0 = P[kiter], rho = P[8 + kiter], mu = P[12 + kiter];
  const float inv = 1.0f / (rho + a0);
  float y[2][4][4];
#pragma unroll
  for (int i = 0; i < 2; ++i)
#pragma unroll
    for (int j = 0; j < 4; ++j) {
      int d = wave * 64 + j * 16 + ln;
      int n4 = m0 + i * 16 + kg * 4;
      size_t idx = base + (size_t)d * NN + n4;
      u16x4 zv = *(const u16x4*)&zb[idx];
      u16x4 es = *(const u16x4*)&eST[idx];
#pragma unroll
      for (int q = 0; q < 4; ++q)
        y[i][j][q] = (acc[i][j][q] + b2f(zv[q]) + rho * logf(b2f(es[q]))) * inv;
    }
  float pm[2][4];
#pragma unroll
  for (int i = 0; i < 2; ++i)
#pragma unroll
    for (int q = 0; q < 4; ++q) {
      float m = fmaxf(fmaxf(y[i][0][q], y[i][1][q]), fmaxf(y[i][2][q], y[i][3][q]));
      m = fmaxf(m, __shfl_xor(m, 1));
      m = fmaxf(m, __shfl_xor(m, 2));
      m = fmaxf(m, __shfl_xor(m, 4));
      m = fmaxf(m, __shfl_xor(m, 8));
      pm[i][q] = m;
    }
  if (ln == 0) {
#pragma unroll
    for (int i = 0; i < 2; ++i)
#pragma unroll
      for (int q = 0; q < 4; ++q) red[wave * 32 + i * 16 + kg * 4 + q] = pm[i][q];
  }
  __syncthreads();
  if (tid < 32)
    red[128 + tid] = fmaxf(fmaxf(red[tid], red[32 + tid]),
                           fmaxf(red[64 + tid], red[96 + tid]));
  __syncthreads();
  float sm[2][4], mc[2][4];
#pragma unroll
  for (int i = 0; i < 2; ++i)
#pragma unroll
    for (int q = 0; q < 4; ++q) {
      mc[i][q] = red[128 + i * 16 + kg * 4 + q];
      float s = expf(y[i][0][q] - mc[i][q]) + expf(y[i][1][q] - mc[i][q]) +
                expf(y[i][2][q] - mc[i][q]) + expf(y[i][3][q] - mc[i][q]);
      s += __shfl_xor(s, 1);
      s += __shfl_xor(s, 2);
      s += __shfl_xor(s, 4);
      s += __shfl_xor(s, 8);
      sm[i][q] = s;
    }
  __syncthreads();
  if (ln == 0) {
#pragma unroll
    for (int i = 0; i < 2; ++i)
#pragma unroll
      for (int q = 0; q < 4; ++q) red[wave * 32 + i * 16 + kg * 4 + q] = sm[i][q];
  }
  __syncthreads();
  if (tid < 32)
    red[160 + tid] = red[128 + tid] +
                     logf(red[tid] + red[32 + tid] + red[64 + tid] + red[96 + tid]);
  __syncthreads();
  float lse[2][4];
#pragma unroll
  for (int i = 0; i < 2; ++i)
#pragma unroll
    for (int q = 0; q < 4; ++q) lse[i][q] = red[160 + i * 16 + kg * 4 + q];

  if (LAST == 0) {
#pragma unroll
    for (int i = 0; i < 2; ++i)
#pragma unroll
      for (int j = 0; j < 4; ++j) {
        int d = wave * 64 + j * 16 + ln;
        int n4 = m0 + i * 16 + kg * 4;
        size_t idx = base + (size_t)d * NN + n4;
        u16x4 et;
#pragma unroll
        for (int q = 0; q < 4; ++q) et[q] = f2b(expf(mu + y[i][j][q] - lse[i][q]));
        *(u16x4*)&eTT[idx] = et;
      }
  } else {
    float p[4] = {0.f, 0.f, 0.f, 0.f};
#pragma unroll
    for (int j = 0; j < 4; ++j)
#pragma unroll
      for (int i = 0; i < 2; ++i) {
        int d = wave * 64 + j * 16 + ln;
        int n4 = m0 + i * 16 + kg * 4;
        size_t idx = base + (size_t)d * NN + n4;
        u16x4 xv = *(const u16x4*)&xTb[idx];
#pragma unroll
        for (int q = 0; q < 4; ++q)
          p[j] += b2f(xv[q]) * expf(mu + y[i][j][q] - lse[i][q]);
      }
#pragma unroll
    for (int j = 0; j < 4; ++j) {
      p[j] += __shfl_xor(p[j], 16);
      p[j] += __shfl_xor(p[j], 32);
    }
    if (kg == 0) {
      size_t pb = ((size_t)b * 16 + blockIdx.y) * DD;
#pragma unroll
      for (int j = 0; j < 4; ++j) part[pb + wave * 64 + j * 16 + ln] = p[j];
    }
  }
}

// ---------- fused S-half: GEMM(x@Mt_S) + S-softmax(axis=n) + z-update [LDS-staged] ----------
template <int ZFIRST>
__global__ __launch_bounds__(512) void k_fs(
    const short* __restrict__ xb, const short* __restrict__ Mtb,
    const short* __restrict__ eTT, short* __restrict__ eST,
    short* __restrict__ zb, const float* __restrict__ P, int kiter) {
  __shared__ short As[512 * 32];
  __shared__ short Bs[32 * 32];
  const int b = blockIdx.x, m0 = blockIdx.y * 32;
  const int tid = threadIdx.x, wave = tid >> 6, lane = tid & 63;
  const int ln = lane & 15, kg = lane >> 4;
  const short* Ab = xb + (size_t)b * ((size_t)NN * DD);
  const short* Bb = Mtb + (size_t)b * ((size_t)DD * DD);
  const size_t base = (size_t)b * ((size_t)NN * DD);

  f32x4 acc[4][2];
#pragma unroll
  for (int i = 0; i < 4; ++i)
#pragma unroll
    for (int j = 0; j < 2; ++j) acc[i][j] = (f32x4){0.f, 0.f, 0.f, 0.f};

  for (int k0 = 0; k0 < DD; k0 += 32) {
    __syncthreads();
#pragma unroll
    for (int c = 0; c < 4; ++c) {
      int row = wave * 64 + c * 16 + (lane >> 2);
      int sg = (lane & 3) ^ (row & 3);
      GLDS(Ab + (size_t)row * DD + k0 + sg * 8, &As[(wave * 64 + c * 16) * 32]);
    }
    if (wave < 2) {
      int row = wave * 16 + (lane >> 2);
      int sg = (lane & 3) ^ (row & 3);
      GLDS(Bb + (size_t)(m0 + row) * DD + k0 + sg * 8, &Bs[(wave * 16) * 32]);
    }
    __syncthreads();
    bf16x8 af[4], bfr[2];
#pragma unroll
    for (int i = 0; i < 4; ++i) {
      int rowA = wave * 64 + i * 16 + ln;
      af[i] = *(const bf16x8*)&As[rowA * 32 + ((kg ^ (rowA & 3)) * 8)];
    }
#pragma unroll
    for (int j = 0; j < 2; ++j) {
      int rowB = j * 16 + ln;
      bfr[j] = *(const bf16x8*)&Bs[rowB * 32 + ((kg ^ (rowB & 3)) * 8)];
    }
#pragma unroll
    for (int i = 0; i < 4; ++i)
#pragma unroll
      for (int j = 0; j < 2; ++j)
        acc[i][j] = __builtin_amdgcn_mfma_f32_16x16x32_bf16(af[i], bfr[j], acc[i][j], 0, 0, 0);
  }
  __syncthreads();
  float* red = (float*)Bs;

  const float rho = P[8 + kiter], eta = P[16 + kiter];
  const float invr = 1.0f / rho;
  float y[4][2][4];
  u16x4 etr[4][2], zr[4][2];
#pragma unroll
  for (int i = 0; i < 4; ++i)
#pragma unroll
    for (int j = 0; j < 2; ++j) {
      int d = m0 + j * 16 + ln;
      int n4 = wave * 64 + i * 16 + kg * 4;
      size_t idx = base + (size_t)d * NN + n4;
      etr[i][j] = *(const u16x4*)&eTT[idx];
      if (!ZFIRST) zr[i][j] = *(const u16x4*)&zb[idx];
#pragma unroll
      for (int q = 0; q < 4; ++q) {
        float zf = ZFIRST ? 0.0f : b2f(zr[i][j][q]);
        y[i][j][q] = (acc[i][j][q] - zf + rho * logf(b2f(etr[i][j][q]))) * invr;
      }
    }
  float pm[2];
#pragma unroll
  for (int j = 0; j < 2; ++j) {
    float m = -1e30f;
#pragma unroll
    for (int i = 0; i < 4; ++i)
#pragma unroll
      for (int q = 0; q < 4; ++q) m = fmaxf(m, y[i][j][q]);
    m = fmaxf(m, __shfl_xor(m, 16));
    m = fmaxf(m, __shfl_xor(m, 32));
    pm[j] = m;
  }
  if (kg == 0) {
#pragma unroll
    for (int j = 0; j < 2; ++j) red[wave * 32 + j * 16 + ln] = pm[j];
  }
  __syncthreads();
  if (tid < 32) {
    float M = red[tid];
#pragma unroll
    for (int w = 1; w < 8; ++w) M = fmaxf(M, red[w * 32 + tid]);
    red[256 + tid] = M;
  }
  __syncthreads();
  float mc[2], ps[2];
#pragma unroll
  for (int j = 0; j < 2; ++j) {
    mc[j] = red[256 + j * 16 + ln];
    float s = 0.f;
#pragma unroll
    for (int i = 0; i < 4; ++i)
#pragma unroll
      for (int q = 0; q < 4; ++q) s += expf(y[i][j][q] - mc[j]);
    s += __shfl_xor(s, 16);
    s += __shfl_xor(s, 32);
    ps[j] = s;
  }
  __syncthreads();
  if (kg == 0) {
#pragma unroll
    for (int j = 0; j < 2; ++j) red[wave * 32 + j * 16 + ln] = ps[j];
  }
  __syncthreads();
  if (tid < 32) {
    float S = 0.f;
#pragma unroll
    for (int w = 0; w < 8; ++w) S += red[w * 32 + tid];
    red[288 + tid] = red[256 + tid] + logf(S);
  }
  __syncthreads();
  float lse[2];
#pragma unroll
  for (int j = 0; j < 2; ++j) lse[j] = red[288 + j * 16 + ln];

#pragma unroll
  for (int i = 0; i < 4; ++i)
#pragma unroll
    for (int j = 0; j < 2; ++j) {
      int d = m0 + j * 16 + ln;
      int n4 = wave * 64 + i * 16 + kg * 4;
      size_t idx = base + (size_t)d * NN + n4;
      u16x4 ev, zo;
#pragma unroll
      for (int q = 0; q < 4; ++q) {
        float es = expf(eta + y[i][j][q] - lse[j]);
        ev[q] = f2b(es);
        float zf = ZFIRST ? 0.0f : b2f(zr[i][j][q]);
        zo[q] = f2b(zf + rho * (b2f(etr[i][j][q]) - es));
      }
      *(u16x4*)&eST[idx] = ev;
      *(u16x4*)&zb[idx] = zo;
    }
}

// ---------- final reduce: out[b][d] = D * sum over 16 partial chunks ----------
__global__ __launch_bounds__(256) void k_out2(const float* __restrict__ part,
                                              float* __restrict__ out) {
  int b = blockIdx.x, d = threadIdx.x;
  float acc = 0.0f;
#pragma unroll
  for (int c = 0; c < 16; ++c) acc += part[((size_t)b * 16 + c) * DD + d];
  out[(size_t)b * DD + d] = (float)DD * acc;
}

// ---------- launch ----------
extern "C" void kernel_launch(void* const* d_in, const int* in_sizes, int n_in,
                              void* d_out, int out_size, void* d_ws, size_t ws_size,
                              hipStream_t stream) {
  const float* x = (const float*)d_in[0];
  const float* a0p = (const float*)d_in[1];
  const float* a1p = (const float*)d_in[2];
  const float* a2p = (const float*)d_in[3];
  const float* a3p = (const float*)d_in[4];
  const float* rhop = (const float*)d_in[5];
  float* out = (float*)d_out;

  const size_t NE = (size_t)BATCH * NN * DD;
  const size_t NE_b = (size_t)NN * DD;
  const size_t C1_b = (size_t)DD * DD;

  float* fws = (float*)d_ws;
  float* S = fws;                   // B*D colsum(x)
  float* s1 = S + BATCH * DD;       // B*D rowsum(c1)
  float* part = s1 + BATCH * DD;    // B*16*DD
  float* P = part + BATCH * 16 * DD;  // 24
  unsigned* keys = (unsigned*)(P + 24);
  short* sws = (short*)(keys + 8);
  short* xb = sws;                  // NE (n-major bf16)
  short* xTb = sws + NE;            // NE (d-major bf16)
  short* eTT = sws + 2 * NE;        // NE (d-major)
  short* eST = sws + 3 * NE;        // NE (d-major)
  short* zb = sws + 4 * NE;         // NE (d-major bf16 dual)
  short* Fb = sws + 5 * NE;         // B*D*D
  short* Mtb = Fb + (size_t)BATCH * C1_b;   // B*D*D
  short* c1b = Mtb + (size_t)BATCH * C1_b;  // B*D*D

  k_prep<<<dim3(4, 8, BATCH), 256, 0, stream>>>(x, xb, xTb, keys);
  k_c1<<<dim3(BATCH, 17), 256, 0, stream>>>(xTb, c1b, keys);
  k_misc<<<2081, 256, 0, stream>>>(c1b, xb, s1, S, a0p, a1p, a2p, a3p, rhop, P, keys);

  // k = 0 T-half: rank-1 shortcut -> eTT
  k_tsm0<<<dim3(BATCH, 8), 512, 0, stream>>>(xTb, S, s1, eTT, P);
  // k = 0 S-half
  k_gemm<512, 1><<<dim3(BATCH, 4, 4), 256, 0, stream>>>(
      xTb, NE_b, NN, eTT, NE_b, NN, (void*)Fb, C1_b, DD, nullptr, 0);
  k_gemm<256, 2><<<dim3(BATCH, 4, 4), 256, 0, stream>>>(
      Fb, C1_b, DD, c1b, C1_b, DD, (void*)Mtb, C1_b, DD, P, 0);
  k_fs<1><<<dim3(BATCH, 8), 512, 0, stream>>>(xb, Mtb, eTT, eST, zb, P, 0);

  for (int k = 1; k <= 2; ++k) {
    // T-half: Mt_T = (a1e/D)(F(eS)@c1)^T + I; fused GEMM+softmax -> eTT
    k_gemm<512, 1><<<dim3(BATCH, 4, 4), 256, 0, stream>>>(
        xTb, NE_b, NN, eST, NE_b, NN, (void*)Fb, C1_b, DD, nullptr, 0);
    k_gemm<256, 3><<<dim3(BATCH, 4, 4), 256, 0, stream>>>(
        Fb, C1_b, DD, c1b, C1_b, DD, (void*)Mtb, C1_b, DD, P, k);
    k_ft<0><<<dim3(BATCH, 16), 256, 0, stream>>>(xb, Mtb, eST, zb, eTT, xTb,
                                                 part, P, k);
    // S-half
    k_gemm<512, 1><<<dim3(BATCH, 4, 4), 256, 0, stream>>>(
        xTb, NE_b, NN, eTT, NE_b, NN, (void*)Fb, C1_b, DD, nullptr, 0);
    k_gemm<256, 2><<<dim3(BATCH, 4, 4), 256, 0, stream>>>(
        Fb, C1_b, DD, c1b, C1_b, DD, (void*)Mtb, C1_b, DD, P, k);
    k_fs<0><<<dim3(BATCH, 8), 512, 0, stream>>>(xb, Mtb, eTT, eST, zb, P, k);
  }

  // k = 3: final T-half -> output partials (tail-trim: S-half dead)
  k_gemm<512, 1><<<dim3(BATCH, 4, 4), 256, 0, stream>>>(
      xTb, NE_b, NN, eST, NE_b, NN, (void*)Fb, C1_b, DD, nullptr, 0);
  k_gemm<256, 3><<<dim3(BATCH, 4, 4), 256, 0, stream>>>(
      Fb, C1_b, DD, c1b, C1_b, DD, (void*)Mtb, C1_b, DD, P, 3);
  k_ft<1><<<dim3(BATCH, 16), 256, 0, stream>>>(xb, Mtb, eST, zb, eTT, xTb,
                                               part, P, 3);
  k_out2<<<BATCH, 256, 0, stream>>>(part, out);
}